// Round 10
// baseline (773.958 us; speedup 1.0000x reference)
//
#include <hip/hip_runtime.h>
#include <hip/hip_bf16.h>
#include <cstdint>

#define T_TOKENS 2048
#define HIDDEN 2048
#define INTER 1408
#define NEXP 16
#define TOPK 4
#define SINTER 2816
#define CAP 768
#define BK 32

typedef __attribute__((ext_vector_type(8))) short short8;
typedef __attribute__((ext_vector_type(8))) unsigned short ushort8;
typedef __attribute__((ext_vector_type(4))) float f32x4;

__device__ __forceinline__ float4 ld4f(const float* p) {
  return *reinterpret_cast<const float4*>(p);
}

__device__ __forceinline__ unsigned short f2bf(float v) {
  unsigned int u = __float_as_uint(v);
  unsigned int r = (u + 0x7FFFu + ((u >> 16) & 1u)) >> 16;  // RNE
  return (unsigned short)r;
}

__device__ __forceinline__ void gld16(const void* g, void* l) {
  __builtin_amdgcn_global_load_lds(
      (const __attribute__((address_space(1))) void*)g,
      (__attribute__((address_space(3))) void*)l, 16, 0, 0);
}

// ---------------- router: logits -> softmax -> top4 ----------------
__global__ __launch_bounds__(64) void router_kernel(
    const float* __restrict__ x, const float* __restrict__ wg,
    int* __restrict__ topi, float* __restrict__ topw)
{
  const int t = blockIdx.x;
  const int lane = threadIdx.x;
  float acc[NEXP];
#pragma unroll
  for (int e = 0; e < NEXP; ++e) acc[e] = 0.f;
  const float* xr = x + (size_t)t * HIDDEN;
  for (int i = lane; i < HIDDEN; i += 64) {
    float xv = xr[i];
#pragma unroll
    for (int e = 0; e < NEXP; ++e) acc[e] += xv * wg[e * HIDDEN + i];
  }
#pragma unroll
  for (int e = 0; e < NEXP; ++e) {
#pragma unroll
    for (int off = 32; off > 0; off >>= 1)
      acc[e] += __shfl_xor(acc[e], off);
  }
  float m = acc[0];
#pragma unroll
  for (int e = 1; e < NEXP; ++e) m = fmaxf(m, acc[e]);
  float p[NEXP];
  float s = 0.f;
#pragma unroll
  for (int e = 0; e < NEXP; ++e) { p[e] = expf(acc[e] - m); s += p[e]; }
  const float inv = 1.f / s;
#pragma unroll
  for (int e = 0; e < NEXP; ++e) p[e] *= inv;
  if (lane == 0) {
#pragma unroll
    for (int k = 0; k < TOPK; ++k) {
      float best = -1.f; int bi = 0;
#pragma unroll
      for (int e = 0; e < NEXP; ++e)
        if (p[e] > best) { best = p[e]; bi = e; }   // strict >: lowest idx on tie
      topi[t * TOPK + k] = bi;
      topw[t * TOPK + k] = best;  // ROUTED_SCALE = 1.0
      p[bi] = -1.f;
    }
  }
}

// ------------- stable partition: slot -> (expert,pos), exact cumsum order -------------
__global__ __launch_bounds__(1024) void partition_kernel(
    const int* __restrict__ topi, float* __restrict__ topw,
    int* __restrict__ rowtok, int* __restrict__ count)
{
  __shared__ int se[T_TOKENS * TOPK];
  for (int i = threadIdx.x; i < T_TOKENS * TOPK; i += 1024) se[i] = topi[i];
  __syncthreads();

  const int wave = threadIdx.x >> 6;
  const int lane = threadIdx.x & 63;
  const uint64_t below = (lane == 0) ? 0ull : ((~0ull) >> (64 - lane));
  int base = 0;
  for (int c = 0; c < T_TOKENS * TOPK; c += 64) {
    int ev = se[c + lane];
    uint64_t mask = __ballot(ev == wave);
    if (ev == wave) {
      int my = base + __popcll(mask & below);
      if (my < CAP) rowtok[wave * CAP + my] = c + lane;
      else          topw[c + lane] = 0.f;
    }
    base += __popcll(mask);
  }
  if (lane == 0) count[wave] = base < CAP ? base : CAP;
}

// ------------- convert x -> bf16 -------------
__global__ __launch_bounds__(256) void cvt_x_kernel(
    const float* __restrict__ x, unsigned short* __restrict__ xb)
{
  const long i = ((long)blockIdx.x * 256 + threadIdx.x) * 8;
  float4 a = ld4f(x + i), b = ld4f(x + i + 4);
  float v[8] = {a.x, a.y, a.z, a.w, b.x, b.y, b.z, b.w};
  unsigned short o[8];
#pragma unroll
  for (int j = 0; j < 8; ++j) o[j] = f2bf(v[j]);
  *(ushort8*)(xb + i) = *(ushort8*)&o[0];
}

// ------------- transpose + convert: W[K][N] -> T[prow(N)][K] bf16 (per expert z) ------
__global__ __launch_bounds__(256) void tcvt_w_kernel(
    const float* __restrict__ W, unsigned short* __restrict__ T,
    int K, int N, long tz, int mul, int which)
{
  const long z = blockIdx.z;
  W += z * (long)K * N;
  T += z * tz;
  const int k0 = blockIdx.x * 64, n0 = blockIdx.y * 64;
  __shared__ float tile[64][65];
  const int tr = threadIdx.x >> 4;
  const int tc4 = (threadIdx.x & 15) * 4;
#pragma unroll
  for (int p = 0; p < 4; ++p) {
    int r = p * 16 + tr;
    float4 v = ld4f(W + (long)(k0 + r) * N + n0 + tc4);
    tile[r][tc4] = v.x; tile[r][tc4 + 1] = v.y;
    tile[r][tc4 + 2] = v.z; tile[r][tc4 + 3] = v.w;
  }
  __syncthreads();
  const int wn = threadIdx.x >> 3;          // 0..31
  const int wk = (threadIdx.x & 7) * 8;     // 0..56
#pragma unroll
  for (int p = 0; p < 2; ++p) {
    int n = p * 32 + wn;
    unsigned short o[8];
#pragma unroll
    for (int j = 0; j < 8; ++j) o[j] = f2bf(tile[wk + j][n]);
    const int gn = n0 + n;
    const long prow = ((long)(gn >> 4) * mul + which) * 16 + (gn & 15);
    *(ushort8*)(T + prow * K + k0 + wk) = *(ushort8*)&o[0];
  }
}

// ------------- 256x256 8-phase bf16 MFMA GEMM (T2+T3+T4+T5) -------------
// BK=64/tile, 2 tiles/iter, 512 thr = 8 waves (2M x 4N), per-wave 128x64 (acc 8x4).
// LDS 128 KiB: 2 dbuf x (A[256][64]+B[256][64]) bf16, 128-B rows, XOR chunk swizzle
// pchunk = c ^ (row&7) -> bank = pchunk*4+word, row-independent -> conflict-free.
// Region ledger (races checked): A unit q = rows {q*64,q*64+128} (last dbuf-read
// p1/p3); B unit q = nh=q 32-row stripes (last read p2/p3). Stage 1 unit/phase,
// always into the non-read dbuf: p0,p1 -> d1(t+1) Aq1,Bq1; p2..p5 -> d0(t+2);
// p6,p7 -> d1(t+3) Aq0,Bq0. vmcnt(4) at p3/p7 (2 units in flight), vmcnt(0) at
// last-iter p3. Every unit lands >=1 end-barrier after its last reader, and is
// vmcnt-confirmed 2+ phases after issue, 4-6 phases before first read.
template<int EPI>   // 0: C fp32; 2: fused SwiGLU (even 16-col blk = gate) -> bf16 H
__global__ __launch_bounds__(512, 2)
void gemm_bf8(const unsigned short* __restrict__ Ag, int ldka,
              const unsigned short* __restrict__ Bg, long bstride,
              float* __restrict__ C, unsigned short* __restrict__ H, int ldc,
              const int* __restrict__ arows_g, int ashift, long aexp,
              const int* __restrict__ crows_g, long cexp,
              const int* __restrict__ cnt, int Mfix, int K,
              int MT, int NTn)
{
  const int nwg = gridDim.x;
  const int lin = (blockIdx.x & 7) * (nwg >> 3) + (blockIdx.x >> 3);
  const int mt = lin % MT;
  const int rest = lin / MT;
  const int nt = rest % NTn;
  const int e = rest / NTn;

  const int M = cnt ? cnt[e] : Mfix;
  if (mt * 256 >= M) return;
  const int n0 = nt * 256;

  const int tid = threadIdx.x;
  const int l = tid & 63;
  const int w = tid >> 6;
  const int wm = w >> 2;        // 0..1
  const int wn = w & 3;         // 0..3
  const int fr = l & 15;
  const int fc = l >> 4;

  const int* arows = arows_g ? arows_g + e * CAP : nullptr;
  const int* crows = crows_g ? crows_g + e * CAP : nullptr;
  const unsigned short* Bexp = Bg + (long)e * bstride;

  __shared__ __align__(16) unsigned short sA[2][256 * 64];
  __shared__ __align__(16) unsigned short sB[2][256 * 64];

  // source chunk pre-swizzle: logical chunk = (l&7) ^ (destrow&7), destrow&7 = (l>>3)&7
  const int sc = ((l & 7) ^ ((l >> 3) & 7)) * 8;

  // A unit q, round j: dest row = j*128 + q*64 + w*8 + (l>>3)
  long aoffq[2][2];
#pragma unroll
  for (int q = 0; q < 2; ++q)
#pragma unroll
    for (int j = 0; j < 2; ++j) {
      const int rloc = j * 128 + q * 64 + w * 8 + (l >> 3);
      int r = mt * 256 + rloc;
      if (r > M - 1) r = M - 1;
      const long arow = arows ? (long)(arows[r] >> ashift) : (aexp * e + r);
      aoffq[q][j] = arow * (long)ldka + sc;
    }
  // B unit q, round j: dest row = j*128 + (w>>2)*64 + q*32 + (w&3)*8 + (l>>3)
  long boffq[2][2];
#pragma unroll
  for (int q = 0; q < 2; ++q)
#pragma unroll
    for (int j = 0; j < 2; ++j) {
      const int rloc = j * 128 + (w >> 2) * 64 + q * 32 + (w & 3) * 8 + (l >> 3);
      boffq[q][j] = (long)(n0 + rloc) * K + sc;
    }

  f32x4 acc[8][4];
#pragma unroll
  for (int i = 0; i < 8; ++i)
#pragma unroll
    for (int j = 0; j < 4; ++j) acc[i][j] = (f32x4)0.f;

  const int NT2 = K / 64;        // 22 or 32 here (even)
  const int NITER = NT2 / 2;

  auto stgAq = [&](int d, int q, int tile) {
#pragma unroll
    for (int j = 0; j < 2; ++j)
      gld16(Ag + aoffq[q][j] + (long)tile * 64,
            &sA[d][(j * 128 + q * 64 + w * 8) * 64]);
  };
  auto stgBq = [&](int d, int q, int tile) {
#pragma unroll
    for (int j = 0; j < 2; ++j)
      gld16(Bexp + boffq[q][j] + (long)tile * 64,
            &sB[d][(j * 128 + (w >> 2) * 64 + q * 32 + (w & 3) * 8) * 64]);
  };

  // prologue: tile0 full -> d0 (8 loads), then t1's Aq0,Bq0 -> d1 (4 loads)
  stgAq(0, 0, 0); stgBq(0, 0, 0); stgAq(0, 1, 0); stgBq(0, 1, 0);
  stgAq(1, 0, 1); stgBq(1, 0, 1);
  asm volatile("s_waitcnt vmcnt(4)" ::: "memory");   // tile0 landed
  __builtin_amdgcn_s_barrier();

  for (int it = 0; it < NITER; ++it) {
    const int t0 = 2 * it;
    const bool notlast = (it + 1 < NITER);
#pragma unroll
    for (int p = 0; p < 8; ++p) {
      const int d = p >> 2;
      const int mh = (p >> 1) & 1;
      const int nh = p & 1;

      // ---- stage one unit (ledger: target region's readers all finished) ----
      if      (p == 0) stgAq(1, 1, t0 + 1);
      else if (p == 1) stgBq(1, 1, t0 + 1);
      else if (notlast) {
        if      (p == 2) stgAq(0, 0, t0 + 2);
        else if (p == 3) stgBq(0, 0, t0 + 2);
        else if (p == 4) stgAq(0, 1, t0 + 2);
        else if (p == 5) stgBq(0, 1, t0 + 2);
        else if (p == 6) stgAq(1, 0, t0 + 3);
        else             stgBq(1, 0, t0 + 3);
      }

      // ---- fragment reads (swizzled) ----
      short8 fa[4][2], fb[2][2];
#pragma unroll
      for (int mi = 0; mi < 4; ++mi)
#pragma unroll
        for (int kk = 0; kk < 2; ++kk) {
          const int row = wm * 128 + mh * 64 + mi * 16 + fr;
          const int pc = (kk * 4 + fc) ^ (fr & 7);
          fa[mi][kk] = *(const short8*)&sA[d][row * 64 + pc * 8];
        }
#pragma unroll
      for (int ni = 0; ni < 2; ++ni)
#pragma unroll
        for (int kk = 0; kk < 2; ++kk) {
          const int row = wn * 64 + nh * 32 + ni * 16 + fr;
          const int pc = (kk * 4 + fc) ^ (fr & 7);
          fb[ni][kk] = *(const short8*)&sB[d][row * 64 + pc * 8];
        }

      __builtin_amdgcn_s_barrier();
      asm volatile("s_waitcnt lgkmcnt(0)" ::: "memory");
      __builtin_amdgcn_sched_barrier(0);
      __builtin_amdgcn_s_setprio(1);
#pragma unroll
      for (int mi = 0; mi < 4; ++mi)
#pragma unroll
        for (int ni = 0; ni < 2; ++ni)
#pragma unroll
          for (int kk = 0; kk < 2; ++kk)
            acc[mh * 4 + mi][nh * 2 + ni] = __builtin_amdgcn_mfma_f32_16x16x32_bf16(
                fa[mi][kk], fb[ni][kk], acc[mh * 4 + mi][nh * 2 + ni], 0, 0, 0);
      __builtin_amdgcn_s_setprio(0);
      if (p == 3) {
        if (notlast) asm volatile("s_waitcnt vmcnt(4)" ::: "memory");
        else         asm volatile("s_waitcnt vmcnt(0)" ::: "memory");
      } else if (p == 7 && notlast) {
        asm volatile("s_waitcnt vmcnt(4)" ::: "memory");
      }
      __builtin_amdgcn_s_barrier();
    }
  }

  // epilogue: C/D layout col=lane&15, row=(lane>>4)*4+rr
#pragma unroll
  for (int mi = 0; mi < 8; ++mi)
#pragma unroll
    for (int rr = 0; rr < 4; ++rr) {
      const int r = mt * 256 + wm * 128 + mi * 16 + fc * 4 + rr;
      if (r >= M) continue;
      const long crow = crows ? (long)crows[r] : (cexp * e + r);
      if constexpr (EPI == 2) {
#pragma unroll
        for (int nh = 0; nh < 2; ++nh) {
          const float g = acc[mi][nh * 2 + 0][rr];
          const float u = acc[mi][nh * 2 + 1][rr];
          const float h = u * (g / (1.f + __expf(-g)));   // silu(g)*u
          const int i = (n0 / 32 + wn * 2 + nh) * 16 + fr;  // logical col
          H[crow * (long)ldc + i] = f2bf(h);
        }
      } else {
#pragma unroll
        for (int nj = 0; nj < 4; ++nj) {
          const int col = n0 + wn * 64 + nj * 16 + fr;
          C[crow * (long)ldc + col] = acc[mi][nj][rr];
        }
      }
    }
}

// ------------- 128x128 depth-2 kernel (proven R6/R8) — used for shared down -------------
template<int EPI>   // 0: C fp32
__global__ __launch_bounds__(256, 2)
void gemm_bf(const unsigned short* __restrict__ Ag, int ldka,
             const unsigned short* __restrict__ Bg, long bstride,
             float* __restrict__ C, unsigned short* __restrict__ H, int ldc,
             const int* __restrict__ arows_g, int ashift, long aexp,
             const int* __restrict__ crows_g, long cexp,
             const int* __restrict__ cnt, int Mfix, int K,
             int MT, int NTn)
{
  const int nwg = gridDim.x;
  const int lin = (blockIdx.x & 7) * (nwg >> 3) + (blockIdx.x >> 3);
  const int mt = lin % MT;
  const int rest = lin / MT;
  const int nt = rest % NTn;
  const int e = rest / NTn;

  const int M = cnt ? cnt[e] : Mfix;
  if (mt * 128 >= M) return;
  const int n0 = nt * 128;

  const int tid = threadIdx.x;
  const int l = tid & 63;
  const int w = tid >> 6;
  const int wm = w >> 1;
  const int wn = w & 1;
  const int fr = l & 15;
  const int fc = l >> 4;

  const int* arows = arows_g ? arows_g + e * CAP : nullptr;
  const int* crows = crows_g ? crows_g + e * CAP : nullptr;
  const unsigned short* Bexp = Bg + (long)e * bstride;

  __shared__ __align__(16) unsigned short sA[3][128 * BK];
  __shared__ __align__(16) unsigned short sB[3][128 * BK];

  const int rb_s = ((l >> 3) & 1) | (((l >> 5) & 1) << 1);
  const int sch = ((l & 3) ^ rb_s) * 8;
  long aoff[2], boff[2];
#pragma unroll
  for (int j = 0; j < 2; ++j) {
    const int rloc = j * 64 + w * 16 + (l >> 2);
    int r = mt * 128 + rloc;
    if (r > M - 1) r = M - 1;
    const long arow = arows ? (long)(arows[r] >> ashift) : (aexp * e + r);
    aoff[j] = arow * (long)ldka + sch;
    boff[j] = (long)(n0 + rloc) * K + sch;
  }

  const int rb_r = ((fr >> 1) & 1) | (((fr >> 3) & 1) << 1);
  const int pcoff = (fc ^ rb_r) * 8;

  f32x4 acc[4][4];
#pragma unroll
  for (int i = 0; i < 4; ++i)
#pragma unroll
    for (int j = 0; j < 4; ++j) acc[i][j] = (f32x4)0.f;

  const int NT = K / BK;

  auto stage = [&](int buf, int kt) {
#pragma unroll
    for (int j = 0; j < 2; ++j) {
      gld16(Ag + aoff[j] + kt, &sA[buf][(j * 64 + w * 16) * BK]);
      gld16(Bexp + boff[j] + kt, &sB[buf][(j * 64 + w * 16) * BK]);
    }
  };

  stage(0, 0);
  stage(1, BK);

  int rb = 0, wb = 2;
  for (int t = 0; t < NT; ++t) {
    if (t + 1 < NT) asm volatile("s_waitcnt vmcnt(4)" ::: "memory");
    else            asm volatile("s_waitcnt vmcnt(0)" ::: "memory");
    __builtin_amdgcn_s_barrier();
    __builtin_amdgcn_sched_barrier(0);

    if (t + 2 < NT) stage(wb, (t + 2) * BK);

    short8 fa[4], fb[4];
#pragma unroll
    for (int mi = 0; mi < 4; ++mi)
      fa[mi] = *(const short8*)&sA[rb][(wm * 64 + mi * 16 + fr) * BK + pcoff];
#pragma unroll
    for (int ni = 0; ni < 4; ++ni)
      fb[ni] = *(const short8*)&sB[rb][(wn * 64 + ni * 16 + fr) * BK + pcoff];
#pragma unroll
    for (int mi = 0; mi < 4; ++mi)
#pragma unroll
      for (int ni = 0; ni < 4; ++ni)
        acc[mi][ni] = __builtin_amdgcn_mfma_f32_16x16x32_bf16(fa[mi], fb[ni], acc[mi][ni], 0, 0, 0);

    rb = (rb == 2) ? 0 : rb + 1;
    wb = (wb == 2) ? 0 : wb + 1;
  }

#pragma unroll
  for (int mi = 0; mi < 4; ++mi)
#pragma unroll
    for (int rr = 0; rr < 4; ++rr) {
      const int r = mt * 128 + wm * 64 + mi * 16 + fc * 4 + rr;
      if (r >= M) continue;
      const long crow = crows ? (long)crows[r] : (cexp * e + r);
#pragma unroll
      for (int ni = 0; ni < 4; ++ni) {
        const int col = n0 + wn * 64 + ni * 16 + fr;
        C[crow * (long)ldc + col] = acc[mi][ni][rr];
      }
    }
}

// ------------- combine: out[t] += sum_k w_k * o_slot[t*4+k] -------------
__global__ __launch_bounds__(256) void combine_kernel(
    const float* __restrict__ o_slot, const float* __restrict__ topw,
    float* __restrict__ out)
{
  const int t = blockIdx.x;
  float w[TOPK];
#pragma unroll
  for (int k = 0; k < TOPK; ++k) w[k] = topw[t * TOPK + k];
  float* orow = out + (size_t)t * HIDDEN;
  for (int c = threadIdx.x * 4; c < HIDDEN; c += 256 * 4) {
    float4 acc = *reinterpret_cast<float4*>(orow + c);
#pragma unroll
    for (int k = 0; k < TOPK; ++k) {
      if (w[k] != 0.f) {
        float4 v = ld4f(o_slot + ((size_t)(t * TOPK + k)) * HIDDEN + c);
        acc.x += w[k] * v.x; acc.y += w[k] * v.y;
        acc.z += w[k] * v.z; acc.w += w[k] * v.w;
      }
    }
    *reinterpret_cast<float4*>(orow + c) = acc;
  }
}

extern "C" void kernel_launch(void* const* d_in, const int* in_sizes, int n_in,
                              void* d_out, int out_size, void* d_ws, size_t ws_size,
                              hipStream_t stream)
{
  const float* x   = (const float*)d_in[0];
  const float* wg  = (const float*)d_in[1];
  const float* w1  = (const float*)d_in[2];
  const float* w3  = (const float*)d_in[3];
  const float* w2  = (const float*)d_in[4];
  const float* ws1 = (const float*)d_in[5];
  const float* ws3 = (const float*)d_in[6];
  const float* ws2 = (const float*)d_in[7];
  float* out = (float*)d_out;

  char* w = (char*)d_ws;
  int*   topi   = (int*)w;   w += (size_t)T_TOKENS * TOPK * 4;
  float* topw   = (float*)w; w += (size_t)T_TOKENS * TOPK * 4;
  int*   rowtok = (int*)w;   w += (size_t)NEXP * CAP * 4;
  int*   count  = (int*)w;   w += 256;
  uintptr_t a = (uintptr_t)w; a = (a + 255) & ~(uintptr_t)255; w = (char*)a;

  const size_t XSZ  = (size_t)T_TOKENS * HIDDEN;            // 4.19M
  const size_t WSI  = (size_t)2 * HIDDEN * SINTER;          // 11.5M  (interleaved ws1/ws3)
  const size_t WRI  = (size_t)2 * NEXP * HIDDEN * INTER;    // 92.3M  (interleaved w1/w3)
  const size_t HSSZ = (size_t)T_TOKENS * SINTER;            // 5.77M
  const size_t HRSZ = (size_t)NEXP * CAP * INTER;           // 17.3M

  unsigned short* xb  = (unsigned short*)w; w += XSZ * 2;   // 8.4 MB
  unsigned short* wSi = (unsigned short*)w; w += WSI * 2;   // 23.1 MB; first half reused as ws2T
  unsigned short* wRi = (unsigned short*)w; w += WRI * 2;   // 184.5 MB; reused: w2T + o_slot
  unsigned short* hs  = (unsigned short*)w; w += HSSZ * 2;  // 11.5 MB
  unsigned short* hr  = (unsigned short*)w; w += HRSZ * 2;  // 34.6 MB
  unsigned short* wS2 = wSi;                                        // after shared upgate GEMM
  unsigned short* wR2 = wRi;                                        // after routed upgate GEMM
  float* o_slot = (float*)(wRi + (size_t)NEXP * HIDDEN * INTER);    // 67.1 MB, after wR2

  router_kernel<<<T_TOKENS, 64, 0, stream>>>(x, wg, topi, topw);
  partition_kernel<<<1, 1024, 0, stream>>>(topi, topw, rowtok, count);
  cvt_x_kernel<<<(int)(XSZ / (256 * 8)), 256, 0, stream>>>(x, xb);

  // ---- shared upgate: hs = silu(x@ws1) * (x@ws3) — 256^2 8-phase, grid 176 ----
  tcvt_w_kernel<<<dim3(HIDDEN / 64, SINTER / 64, 1), 256, 0, stream>>>(
      ws1, wSi, HIDDEN, SINTER, 0L, 2, 0);
  tcvt_w_kernel<<<dim3(HIDDEN / 64, SINTER / 64, 1), 256, 0, stream>>>(
      ws3, wSi, HIDDEN, SINTER, 0L, 2, 1);
  gemm_bf8<2><<<(T_TOKENS / 256) * (2 * SINTER / 256), 512, 0, stream>>>(
      xb, HIDDEN, wSi, 0L, nullptr, hs, SINTER,
      nullptr, 0, 0L, nullptr, 0L,
      nullptr, T_TOKENS, HIDDEN, T_TOKENS / 256, 2 * SINTER / 256);

  // ---- routed upgate: hr = silu(gx@w1[e]) * (gx@w3[e]) — 256^2 8-phase, grid 528 ----
  tcvt_w_kernel<<<dim3(HIDDEN / 64, INTER / 64, NEXP), 256, 0, stream>>>(
      w1, wRi, HIDDEN, INTER, (long)2 * HIDDEN * INTER, 2, 0);
  tcvt_w_kernel<<<dim3(HIDDEN / 64, INTER / 64, NEXP), 256, 0, stream>>>(
      w3, wRi, HIDDEN, INTER, (long)2 * HIDDEN * INTER, 2, 1);
  gemm_bf8<2><<<(CAP / 256) * (2 * INTER / 256) * NEXP, 512, 0, stream>>>(
      xb, HIDDEN, wRi, (long)2 * HIDDEN * INTER, nullptr, hr, INTER,
      rowtok, 2, 0L, nullptr, (long)CAP,
      count, 0, HIDDEN, CAP / 256, 2 * INTER / 256);

  // ---- shared down: out = hs @ ws2 — proven 128^2 kernel, grid 256 ----
  tcvt_w_kernel<<<dim3(SINTER / 64, HIDDEN / 64, 1), 256, 0, stream>>>(
      ws2, wS2, SINTER, HIDDEN, 0L, 1, 0);
  gemm_bf<0><<<(T_TOKENS / 128) * (HIDDEN / 128), 256, 0, stream>>>(
      hs, SINTER, wS2, 0L, out, nullptr, HIDDEN,
      nullptr, 0, 0L, nullptr, 0L,
      nullptr, T_TOKENS, SINTER, T_TOKENS / 128, HIDDEN / 128);

  // ---- routed down: o_slot = hr @ w2[e] — 256^2 8-phase, grid 384 ----
  tcvt_w_kernel<<<dim3(INTER / 64, HIDDEN / 64, NEXP), 256, 0, stream>>>(
      w2, wR2, INTER, HIDDEN, (long)INTER * HIDDEN, 1, 0);
  gemm_bf8<0><<<(CAP / 256) * (HIDDEN / 256) * NEXP, 512, 0, stream>>>(
      hr, INTER, wR2, (long)INTER * HIDDEN, o_slot, nullptr, HIDDEN,
      nullptr, 0, (long)CAP, rowtok, 0L,
      count, 0, INTER, CAP / 256, HIDDEN / 256);

  combine_kernel<<<T_TOKENS, 256, 0, stream>>>(o_slot, topw, out);
}

// Round 11
// 696.635 us; speedup vs baseline: 1.1110x; 1.1110x over previous
//
#include <hip/hip_runtime.h>
#include <hip/hip_bf16.h>
#include <cstdint>

#define T_TOKENS 2048
#define HIDDEN 2048
#define INTER 1408
#define NEXP 16
#define TOPK 4
#define SINTER 2816
#define CAP 768
#define BK 32

typedef __attribute__((ext_vector_type(8))) short short8;
typedef __attribute__((ext_vector_type(8))) unsigned short ushort8;
typedef __attribute__((ext_vector_type(4))) float f32x4;

__device__ __forceinline__ float4 ld4f(const float* p) {
  return *reinterpret_cast<const float4*>(p);
}

__device__ __forceinline__ unsigned short f2bf(float v) {
  unsigned int u = __float_as_uint(v);
  unsigned int r = (u + 0x7FFFu + ((u >> 16) & 1u)) >> 16;  // RNE
  return (unsigned short)r;
}

__device__ __forceinline__ void gld16(const void* g, void* l) {
  __builtin_amdgcn_global_load_lds(
      (const __attribute__((address_space(1))) void*)g,
      (__attribute__((address_space(3))) void*)l, 16, 0, 0);
}

// ---------------- router: logits -> softmax -> top4 ----------------
__global__ __launch_bounds__(64) void router_kernel(
    const float* __restrict__ x, const float* __restrict__ wg,
    int* __restrict__ topi, float* __restrict__ topw)
{
  const int t = blockIdx.x;
  const int lane = threadIdx.x;
  float acc[NEXP];
#pragma unroll
  for (int e = 0; e < NEXP; ++e) acc[e] = 0.f;
  const float* xr = x + (size_t)t * HIDDEN;
  for (int i = lane; i < HIDDEN; i += 64) {
    float xv = xr[i];
#pragma unroll
    for (int e = 0; e < NEXP; ++e) acc[e] += xv * wg[e * HIDDEN + i];
  }
#pragma unroll
  for (int e = 0; e < NEXP; ++e) {
#pragma unroll
    for (int off = 32; off > 0; off >>= 1)
      acc[e] += __shfl_xor(acc[e], off);
  }
  float m = acc[0];
#pragma unroll
  for (int e = 1; e < NEXP; ++e) m = fmaxf(m, acc[e]);
  float p[NEXP];
  float s = 0.f;
#pragma unroll
  for (int e = 0; e < NEXP; ++e) { p[e] = expf(acc[e] - m); s += p[e]; }
  const float inv = 1.f / s;
#pragma unroll
  for (int e = 0; e < NEXP; ++e) p[e] *= inv;
  if (lane == 0) {
#pragma unroll
    for (int k = 0; k < TOPK; ++k) {
      float best = -1.f; int bi = 0;
#pragma unroll
      for (int e = 0; e < NEXP; ++e)
        if (p[e] > best) { best = p[e]; bi = e; }   // strict >: lowest idx on tie
      topi[t * TOPK + k] = bi;
      topw[t * TOPK + k] = best;  // ROUTED_SCALE = 1.0
      p[bi] = -1.f;
    }
  }
}

// ------------- stable partition: slot -> (expert,pos), exact cumsum order -------------
__global__ __launch_bounds__(1024) void partition_kernel(
    const int* __restrict__ topi, float* __restrict__ topw,
    int* __restrict__ rowtok, int* __restrict__ count)
{
  __shared__ int se[T_TOKENS * TOPK];
  for (int i = threadIdx.x; i < T_TOKENS * TOPK; i += 1024) se[i] = topi[i];
  __syncthreads();

  const int wave = threadIdx.x >> 6;
  const int lane = threadIdx.x & 63;
  const uint64_t below = (lane == 0) ? 0ull : ((~0ull) >> (64 - lane));
  int base = 0;
  for (int c = 0; c < T_TOKENS * TOPK; c += 64) {
    int ev = se[c + lane];
    uint64_t mask = __ballot(ev == wave);
    if (ev == wave) {
      int my = base + __popcll(mask & below);
      if (my < CAP) rowtok[wave * CAP + my] = c + lane;
      else          topw[c + lane] = 0.f;
    }
    base += __popcll(mask);
  }
  if (lane == 0) count[wave] = base < CAP ? base : CAP;
}

// ------------- convert x -> bf16 -------------
__global__ __launch_bounds__(256) void cvt_x_kernel(
    const float* __restrict__ x, unsigned short* __restrict__ xb)
{
  const long i = ((long)blockIdx.x * 256 + threadIdx.x) * 8;
  float4 a = ld4f(x + i), b = ld4f(x + i + 4);
  float v[8] = {a.x, a.y, a.z, a.w, b.x, b.y, b.z, b.w};
  unsigned short o[8];
#pragma unroll
  for (int j = 0; j < 8; ++j) o[j] = f2bf(v[j]);
  *(ushort8*)(xb + i) = *(ushort8*)&o[0];
}

// ------------- transpose + convert: W[K][N] -> T[prow(N)][K] bf16 (per expert z) ------
__global__ __launch_bounds__(256) void tcvt_w_kernel(
    const float* __restrict__ W, unsigned short* __restrict__ T,
    int K, int N, long tz, int mul, int which)
{
  const long z = blockIdx.z;
  W += z * (long)K * N;
  T += z * tz;
  const int k0 = blockIdx.x * 64, n0 = blockIdx.y * 64;
  __shared__ float tile[64][65];
  const int tr = threadIdx.x >> 4;
  const int tc4 = (threadIdx.x & 15) * 4;
#pragma unroll
  for (int p = 0; p < 4; ++p) {
    int r = p * 16 + tr;
    float4 v = ld4f(W + (long)(k0 + r) * N + n0 + tc4);
    tile[r][tc4] = v.x; tile[r][tc4 + 1] = v.y;
    tile[r][tc4 + 2] = v.z; tile[r][tc4 + 3] = v.w;
  }
  __syncthreads();
  const int wn = threadIdx.x >> 3;          // 0..31
  const int wk = (threadIdx.x & 7) * 8;     // 0..56
#pragma unroll
  for (int p = 0; p < 2; ++p) {
    int n = p * 32 + wn;
    unsigned short o[8];
#pragma unroll
    for (int j = 0; j < 8; ++j) o[j] = f2bf(tile[wk + j][n]);
    const int gn = n0 + n;
    const long prow = ((long)(gn >> 4) * mul + which) * 16 + (gn & 15);
    *(ushort8*)(T + prow * K + k0 + wk) = *(ushort8*)&o[0];
  }
}

// ------------- 256x128 bf16 MFMA GEMM, depth-2 counted prefetch, swizzled LDS -------
// Block 256x128, BK=32, 256 thr = 4 waves (2M x 2N), per-wave 128x64 out (acc 8x4).
// 12 ds_read_b128 feed 32 MFMA per K-step (0.375 reads/MFMA — m201 ratio) in the
// PROVEN R8 2-phase counted-vmcnt pipeline. 3-buffer LDS (72 KB -> 2 blocks/CU).
// Iter t: vmcnt(6) [stage(t) done, issued 2 iters ago] -> barrier -> stage(t+2)
// -> 12 ds_read -> 32 MFMA. XOR chunk swizzle (R5/R6-verified): 0 conflicts.
// EPI=0: C fp32. EPI=2: fused SwiGLU on 16-col-interleaved B -> bf16 H.
template<int EPI>
__global__ __launch_bounds__(256, 2)
void gemm_bf2(const unsigned short* __restrict__ Ag, int ldka,
              const unsigned short* __restrict__ Bg, long bstride,
              float* __restrict__ C, unsigned short* __restrict__ H, int ldc,
              const int* __restrict__ arows_g, int ashift, long aexp,
              const int* __restrict__ crows_g, long cexp,
              const int* __restrict__ cnt, int Mfix, int K,
              int MT, int NTn)
{
  const int nwg = gridDim.x;
  const int lin = (blockIdx.x & 7) * (nwg >> 3) + (blockIdx.x >> 3);
  const int mt = lin % MT;
  const int rest = lin / MT;
  const int nt = rest % NTn;
  const int e = rest / NTn;

  const int M = cnt ? cnt[e] : Mfix;
  if (mt * 256 >= M) return;
  const int n0 = nt * 128;

  const int tid = threadIdx.x;
  const int l = tid & 63;
  const int w = tid >> 6;       // 0..3
  const int wm = w >> 1;        // 0..1 -> rows wm*128
  const int wn = w & 1;         // 0..1 -> cols wn*64
  const int fr = l & 15;
  const int fc = l >> 4;

  const int* arows = arows_g ? arows_g + e * CAP : nullptr;
  const int* crows = crows_g ? crows_g + e * CAP : nullptr;
  const unsigned short* Bexp = Bg + (long)e * bstride;

  __shared__ __align__(16) unsigned short sA[3][256 * BK];   // 48 KB
  __shared__ __align__(16) unsigned short sB[3][128 * BK];   // 24 KB

  // staging: round j covers rows j*64 + w*16 .. +15; lane l -> row +(l>>2), chunk l&3.
  // pre-swizzle source chunk by dest-row bits {1,3} (= bits of l>>2):
  const int rb_s = ((l >> 3) & 1) | (((l >> 5) & 1) << 1);
  const int sch = ((l & 3) ^ rb_s) * 8;
  long aoff[4], boff[2];
#pragma unroll
  for (int j = 0; j < 4; ++j) {
    const int rloc = j * 64 + w * 16 + (l >> 2);   // 0..255
    int r = mt * 256 + rloc;
    if (r > M - 1) r = M - 1;
    const long arow = arows ? (long)(arows[r] >> ashift) : (aexp * e + r);
    aoff[j] = arow * (long)ldka + sch;
  }
#pragma unroll
  for (int j = 0; j < 2; ++j) {
    const int rloc = j * 64 + w * 16 + (l >> 2);   // 0..127
    boff[j] = (long)(n0 + rloc) * K + sch;
  }

  // fragment-read swizzle: physical chunk = fc ^ bits{1,3}(fr)
  const int rb_r = ((fr >> 1) & 1) | (((fr >> 3) & 1) << 1);
  const int pcoff = (fc ^ rb_r) * 8;

  f32x4 acc[8][4];
#pragma unroll
  for (int i = 0; i < 8; ++i)
#pragma unroll
    for (int j = 0; j < 4; ++j) acc[i][j] = (f32x4)0.f;

  const int NT = K / BK;

  auto stage = [&](int buf, int kt) {
#pragma unroll
    for (int j = 0; j < 4; ++j)
      gld16(Ag + aoff[j] + kt, &sA[buf][(j * 64 + w * 16) * BK]);
#pragma unroll
    for (int j = 0; j < 2; ++j)
      gld16(Bexp + boff[j] + kt, &sB[buf][(j * 64 + w * 16) * BK]);
  };

  stage(0, 0);
  stage(1, BK);

  int rb = 0, wb = 2;
  for (int t = 0; t < NT; ++t) {
    // stage(t) (6 loads) was issued two iters ago; allow stage(t+1) to stay in flight.
    if (t + 1 < NT) asm volatile("s_waitcnt vmcnt(6)" ::: "memory");
    else            asm volatile("s_waitcnt vmcnt(0)" ::: "memory");
    __builtin_amdgcn_s_barrier();          // all waves' stage(t) landed; all prior
    __builtin_amdgcn_sched_barrier(0);     // reads of buf[wb] done

    if (t + 2 < NT) stage(wb, (t + 2) * BK);

    short8 fa[8], fb[4];
#pragma unroll
    for (int mi = 0; mi < 8; ++mi)
      fa[mi] = *(const short8*)&sA[rb][(wm * 128 + mi * 16 + fr) * BK + pcoff];
#pragma unroll
    for (int ni = 0; ni < 4; ++ni)
      fb[ni] = *(const short8*)&sB[rb][(wn * 64 + ni * 16 + fr) * BK + pcoff];
#pragma unroll
    for (int mi = 0; mi < 8; ++mi)
#pragma unroll
      for (int ni = 0; ni < 4; ++ni)
        acc[mi][ni] = __builtin_amdgcn_mfma_f32_16x16x32_bf16(fa[mi], fb[ni], acc[mi][ni], 0, 0, 0);

    rb = (rb == 2) ? 0 : rb + 1;
    wb = (wb == 2) ? 0 : wb + 1;
  }

  // epilogue: C/D layout col=lane&15, row=(lane>>4)*4+rr
#pragma unroll
  for (int mi = 0; mi < 8; ++mi)
#pragma unroll
    for (int rr = 0; rr < 4; ++rr) {
      const int r = mt * 256 + wm * 128 + mi * 16 + fc * 4 + rr;
      if (r >= M) continue;
      const long crow = crows ? (long)crows[r] : (cexp * e + r);
      if constexpr (EPI == 2) {
#pragma unroll
        for (int np = 0; np < 2; ++np) {
          const float g = acc[mi][2 * np][rr];
          const float u = acc[mi][2 * np + 1][rr];
          const float h = u * (g / (1.f + __expf(-g)));   // silu(g)*u
          const int i = (n0 / 32 + wn * 2 + np) * 16 + fr;  // logical col
          H[crow * (long)ldc + i] = f2bf(h);
        }
      } else {
#pragma unroll
        for (int ni = 0; ni < 4; ++ni) {
          const int col = n0 + wn * 64 + ni * 16 + fr;
          C[crow * (long)ldc + col] = acc[mi][ni][rr];
        }
      }
    }
}

// ------------- 128x128 depth-2 kernel (proven R6/R8) — used for shared down -------------
template<int EPI>   // 0: C fp32
__global__ __launch_bounds__(256, 2)
void gemm_bf(const unsigned short* __restrict__ Ag, int ldka,
             const unsigned short* __restrict__ Bg, long bstride,
             float* __restrict__ C, unsigned short* __restrict__ H, int ldc,
             const int* __restrict__ arows_g, int ashift, long aexp,
             const int* __restrict__ crows_g, long cexp,
             const int* __restrict__ cnt, int Mfix, int K,
             int MT, int NTn)
{
  const int nwg = gridDim.x;
  const int lin = (blockIdx.x & 7) * (nwg >> 3) + (blockIdx.x >> 3);
  const int mt = lin % MT;
  const int rest = lin / MT;
  const int nt = rest % NTn;
  const int e = rest / NTn;

  const int M = cnt ? cnt[e] : Mfix;
  if (mt * 128 >= M) return;
  const int n0 = nt * 128;

  const int tid = threadIdx.x;
  const int l = tid & 63;
  const int w = tid >> 6;
  const int wm = w >> 1;
  const int wn = w & 1;
  const int fr = l & 15;
  const int fc = l >> 4;

  const int* arows = arows_g ? arows_g + e * CAP : nullptr;
  const int* crows = crows_g ? crows_g + e * CAP : nullptr;
  const unsigned short* Bexp = Bg + (long)e * bstride;

  __shared__ __align__(16) unsigned short sA[3][128 * BK];
  __shared__ __align__(16) unsigned short sB[3][128 * BK];

  const int rb_s = ((l >> 3) & 1) | (((l >> 5) & 1) << 1);
  const int sch = ((l & 3) ^ rb_s) * 8;
  long aoff[2], boff[2];
#pragma unroll
  for (int j = 0; j < 2; ++j) {
    const int rloc = j * 64 + w * 16 + (l >> 2);
    int r = mt * 128 + rloc;
    if (r > M - 1) r = M - 1;
    const long arow = arows ? (long)(arows[r] >> ashift) : (aexp * e + r);
    aoff[j] = arow * (long)ldka + sch;
    boff[j] = (long)(n0 + rloc) * K + sch;
  }

  const int rb_r = ((fr >> 1) & 1) | (((fr >> 3) & 1) << 1);
  const int pcoff = (fc ^ rb_r) * 8;

  f32x4 acc[4][4];
#pragma unroll
  for (int i = 0; i < 4; ++i)
#pragma unroll
    for (int j = 0; j < 4; ++j) acc[i][j] = (f32x4)0.f;

  const int NT = K / BK;

  auto stage = [&](int buf, int kt) {
#pragma unroll
    for (int j = 0; j < 2; ++j) {
      gld16(Ag + aoff[j] + kt, &sA[buf][(j * 64 + w * 16) * BK]);
      gld16(Bexp + boff[j] + kt, &sB[buf][(j * 64 + w * 16) * BK]);
    }
  };

  stage(0, 0);
  stage(1, BK);

  int rb = 0, wb = 2;
  for (int t = 0; t < NT; ++t) {
    if (t + 1 < NT) asm volatile("s_waitcnt vmcnt(4)" ::: "memory");
    else            asm volatile("s_waitcnt vmcnt(0)" ::: "memory");
    __builtin_amdgcn_s_barrier();
    __builtin_amdgcn_sched_barrier(0);

    if (t + 2 < NT) stage(wb, (t + 2) * BK);

    short8 fa[4], fb[4];
#pragma unroll
    for (int mi = 0; mi < 4; ++mi)
      fa[mi] = *(const short8*)&sA[rb][(wm * 64 + mi * 16 + fr) * BK + pcoff];
#pragma unroll
    for (int ni = 0; ni < 4; ++ni)
      fb[ni] = *(const short8*)&sB[rb][(wn * 64 + ni * 16 + fr) * BK + pcoff];
#pragma unroll
    for (int mi = 0; mi < 4; ++mi)
#pragma unroll
      for (int ni = 0; ni < 4; ++ni)
        acc[mi][ni] = __builtin_amdgcn_mfma_f32_16x16x32_bf16(fa[mi], fb[ni], acc[mi][ni], 0, 0, 0);

    rb = (rb == 2) ? 0 : rb + 1;
    wb = (wb == 2) ? 0 : wb + 1;
  }

#pragma unroll
  for (int mi = 0; mi < 4; ++mi)
#pragma unroll
    for (int rr = 0; rr < 4; ++rr) {
      const int r = mt * 128 + wm * 64 + mi * 16 + fc * 4 + rr;
      if (r >= M) continue;
      const long crow = crows ? (long)crows[r] : (cexp * e + r);
#pragma unroll
      for (int ni = 0; ni < 4; ++ni) {
        const int col = n0 + wn * 64 + ni * 16 + fr;
        C[crow * (long)ldc + col] = acc[mi][ni][rr];
      }
    }
}

// ------------- combine: out[t] += sum_k w_k * o_slot[t*4+k] -------------
__global__ __launch_bounds__(256) void combine_kernel(
    const float* __restrict__ o_slot, const float* __restrict__ topw,
    float* __restrict__ out)
{
  const int t = blockIdx.x;
  float w[TOPK];
#pragma unroll
  for (int k = 0; k < TOPK; ++k) w[k] = topw[t * TOPK + k];
  float* orow = out + (size_t)t * HIDDEN;
  for (int c = threadIdx.x * 4; c < HIDDEN; c += 256 * 4) {
    float4 acc = *reinterpret_cast<float4*>(orow + c);
#pragma unroll
    for (int k = 0; k < TOPK; ++k) {
      if (w[k] != 0.f) {
        float4 v = ld4f(o_slot + ((size_t)(t * TOPK + k)) * HIDDEN + c);
        acc.x += w[k] * v.x; acc.y += w[k] * v.y;
        acc.z += w[k] * v.z; acc.w += w[k] * v.w;
      }
    }
    *reinterpret_cast<float4*>(orow + c) = acc;
  }
}

extern "C" void kernel_launch(void* const* d_in, const int* in_sizes, int n_in,
                              void* d_out, int out_size, void* d_ws, size_t ws_size,
                              hipStream_t stream)
{
  const float* x   = (const float*)d_in[0];
  const float* wg  = (const float*)d_in[1];
  const float* w1  = (const float*)d_in[2];
  const float* w3  = (const float*)d_in[3];
  const float* w2  = (const float*)d_in[4];
  const float* ws1 = (const float*)d_in[5];
  const float* ws3 = (const float*)d_in[6];
  const float* ws2 = (const float*)d_in[7];
  float* out = (float*)d_out;

  char* w = (char*)d_ws;
  int*   topi   = (int*)w;   w += (size_t)T_TOKENS * TOPK * 4;
  float* topw   = (float*)w; w += (size_t)T_TOKENS * TOPK * 4;
  int*   rowtok = (int*)w;   w += (size_t)NEXP * CAP * 4;
  int*   count  = (int*)w;   w += 256;
  uintptr_t a = (uintptr_t)w; a = (a + 255) & ~(uintptr_t)255; w = (char*)a;

  const size_t XSZ  = (size_t)T_TOKENS * HIDDEN;            // 4.19M
  const size_t WSI  = (size_t)2 * HIDDEN * SINTER;          // 11.5M  (interleaved ws1/ws3)
  const size_t WRI  = (size_t)2 * NEXP * HIDDEN * INTER;    // 92.3M  (interleaved w1/w3)
  const size_t HSSZ = (size_t)T_TOKENS * SINTER;            // 5.77M
  const size_t HRSZ = (size_t)NEXP * CAP * INTER;           // 17.3M

  unsigned short* xb  = (unsigned short*)w; w += XSZ * 2;   // 8.4 MB
  unsigned short* wSi = (unsigned short*)w; w += WSI * 2;   // 23.1 MB; first half reused as ws2T
  unsigned short* wRi = (unsigned short*)w; w += WRI * 2;   // 184.5 MB; reused: w2T + o_slot
  unsigned short* hs  = (unsigned short*)w; w += HSSZ * 2;  // 11.5 MB
  unsigned short* hr  = (unsigned short*)w; w += HRSZ * 2;  // 34.6 MB
  unsigned short* wS2 = wSi;                                        // after shared upgate GEMM
  unsigned short* wR2 = wRi;                                        // after routed upgate GEMM
  float* o_slot = (float*)(wRi + (size_t)NEXP * HIDDEN * INTER);    // 67.1 MB, after wR2

  router_kernel<<<T_TOKENS, 64, 0, stream>>>(x, wg, topi, topw);
  partition_kernel<<<1, 1024, 0, stream>>>(topi, topw, rowtok, count);
  cvt_x_kernel<<<(int)(XSZ / (256 * 8)), 256, 0, stream>>>(x, xb);

  // ---- shared upgate: hs = silu(x@ws1) * (x@ws3) — 256x128, grid 352 ----
  tcvt_w_kernel<<<dim3(HIDDEN / 64, SINTER / 64, 1), 256, 0, stream>>>(
      ws1, wSi, HIDDEN, SINTER, 0L, 2, 0);
  tcvt_w_kernel<<<dim3(HIDDEN / 64, SINTER / 64, 1), 256, 0, stream>>>(
      ws3, wSi, HIDDEN, SINTER, 0L, 2, 1);
  gemm_bf2<2><<<(T_TOKENS / 256) * (2 * SINTER / 128), 256, 0, stream>>>(
      xb, HIDDEN, wSi, 0L, nullptr, hs, SINTER,
      nullptr, 0, 0L, nullptr, 0L,
      nullptr, T_TOKENS, HIDDEN, T_TOKENS / 256, 2 * SINTER / 128);

  // ---- routed upgate: hr = silu(gx@w1[e]) * (gx@w3[e]) — 256x128, grid 1056 ----
  tcvt_w_kernel<<<dim3(HIDDEN / 64, INTER / 64, NEXP), 256, 0, stream>>>(
      w1, wRi, HIDDEN, INTER, (long)2 * HIDDEN * INTER, 2, 0);
  tcvt_w_kernel<<<dim3(HIDDEN / 64, INTER / 64, NEXP), 256, 0, stream>>>(
      w3, wRi, HIDDEN, INTER, (long)2 * HIDDEN * INTER, 2, 1);
  gemm_bf2<2><<<(CAP / 256) * (2 * INTER / 128) * NEXP, 256, 0, stream>>>(
      xb, HIDDEN, wRi, (long)2 * HIDDEN * INTER, nullptr, hr, INTER,
      rowtok, 2, 0L, nullptr, (long)CAP,
      count, 0, HIDDEN, CAP / 256, 2 * INTER / 128);

  // ---- shared down: out = hs @ ws2 — proven 128^2 kernel, grid 256 ----
  tcvt_w_kernel<<<dim3(SINTER / 64, HIDDEN / 64, 1), 256, 0, stream>>>(
      ws2, wS2, SINTER, HIDDEN, 0L, 1, 0);
  gemm_bf<0><<<(T_TOKENS / 128) * (HIDDEN / 128), 256, 0, stream>>>(
      hs, SINTER, wS2, 0L, out, nullptr, HIDDEN,
      nullptr, 0, 0L, nullptr, 0L,
      nullptr, T_TOKENS, SINTER, T_TOKENS / 128, HIDDEN / 128);

  // ---- routed down: o_slot = hr @ w2[e] — 256x128, grid 768 ----
  tcvt_w_kernel<<<dim3(INTER / 64, HIDDEN / 64, NEXP), 256, 0, stream>>>(
      w2, wR2, INTER, HIDDEN, (long)INTER * HIDDEN, 1, 0);
  gemm_bf2<0><<<(CAP / 256) * (HIDDEN / 128) * NEXP, 256, 0, stream>>>(
      hr, INTER, wR2, (long)INTER * HIDDEN, o_slot, nullptr, HIDDEN,
      nullptr, 0, (long)CAP, rowtok, 0L,
      count, 0, INTER, CAP / 256, HIDDEN / 128);

  combine_kernel<<<T_TOKENS, 256, 0, stream>>>(o_slot, topw, out);
}